// Round 3
// baseline (147.087 us; speedup 1.0000x reference)
//
#include <hip/hip_runtime.h>
#include <hip/hip_bf16.h>

// PQ embedding gather (all reference dtypes preserved, ints as int32):
//   out[t, m*32 + j] = centroids[m, item_codes[ids[t], m], j]
// B*S = 102400 tokens, M = 8 code bytes, SUB = 32 floats, 256 centroids/byte.
//   ids:       int32   [B*S]            (harness converts jnp.int64 -> int32)
//   item_codes:int32   [(N+1)*8]
//   centroids: float32 [8*256*32]       (256 KB, cache-resident)
//   out:       float32 [B*S*256]

#define M_BYTES 8
#define SUB_DIM 32
#define EMB     (M_BYTES * SUB_DIM)   // 256 floats per token

__global__ __launch_bounds__(256) void ItemCodeLayer_30253749633338_kernel(
    const int*   __restrict__ ids,    // [B*S]
    const int*   __restrict__ codes,  // [(N+1)*M]
    const float* __restrict__ cent,   // [M*256*SUB]
    float*       __restrict__ out,    // [B*S*EMB]
    int n_tokens)
{
    const int tid = blockIdx.x * blockDim.x + threadIdx.x;
    // 64 lanes per token, 16 B (4 floats) per lane -> 256 floats/token.
    const int token = tid >> 6;
    if (token >= n_tokens) return;
    const int l = tid & 63;
    const int m = l >> 3;            // 0..7 : which code byte (8 lanes each)
    const int j = (l & 7) * 4;       // 0,4,...,28 : float offset within sub-embedding

    const int id   = ids[token];
    const int code = codes[(size_t)id * M_BYTES + m];  // same-line broadcast across 8 lanes

    // 16B-aligned vector load from the codebook (256 KB total, L2-resident)
    const float4* src = reinterpret_cast<const float4*>(
        cent + ((size_t)(m * 256 + code) * SUB_DIM + j));
    float4 v = *src;

    // contiguous 1 KB store per wave
    float4* dst = reinterpret_cast<float4*>(
        out + ((size_t)token * EMB + m * SUB_DIM + j));
    *dst = v;
}

extern "C" void kernel_launch(void* const* d_in, const int* in_sizes, int n_in,
                              void* d_out, int out_size, void* d_ws, size_t ws_size,
                              hipStream_t stream) {
    const int*   ids   = (const int*)  d_in[0];   // input_ids  [B*S] int32
    const int*   codes = (const int*)  d_in[1];   // item_codes [(N+1)*M] int32
    const float* cent  = (const float*)d_in[2];   // centroids  [M*256*SUB] float32
    float*       out   = (float*)      d_out;

    const int n_tokens = in_sizes[0];             // 102400 tokens
    const long long total_threads = (long long)n_tokens * 64;
    const int block = 256;
    const int grid  = (int)((total_threads + block - 1) / block);

    hipLaunchKernelGGL(ItemCodeLayer_30253749633338_kernel,
                       dim3(grid), dim3(block), 0, stream,
                       ids, codes, cent, out, n_tokens);
}

// Round 4
// 131.078 us; speedup vs baseline: 1.1221x; 1.1221x over previous
//
#include <hip/hip_runtime.h>
#include <hip/hip_bf16.h>

// PQ embedding gather:
//   out[t, m*32 + j] = centroids[m, item_codes[ids[t], m], j]
// B*S = 102400 tokens, M = 8 code bytes, SUB = 32 floats, 256 centroids/byte.
//   ids:       int32   [B*S]
//   item_codes:int32   [(N+1)*8]    (32 MB, random-row gather -> the latency hazard)
//   centroids: float32 [8*256*32]   (256 KB, L2-resident)
//   out:       float32 [B*S*256]    (105 MB, streaming write)
//
// Design: 64 tokens per 256-thread block.
//   Phase A: 2 independent random code-row gathers per thread (64 rows/block
//            all in flight at once) -> LDS.  This replaces the previous
//            one-dependent-chain-per-wave structure (latency-bound).
//   Phase B: each wave writes 16 tokens, unroll x4 -> 4 independent
//            centroid-gather/store chains per thread.

#define M_BYTES 8
#define SUB_DIM 32
#define EMB     (M_BYTES * SUB_DIM)   // 256 floats per token
#define TOK_PER_BLOCK 64
#define BLOCK 256

__global__ __launch_bounds__(BLOCK) void ItemCodeLayer_30253749633338_kernel(
    const int*   __restrict__ ids,    // [B*S]
    const int*   __restrict__ codes,  // [(N+1)*M]
    const float* __restrict__ cent,   // [M*256*SUB]
    float*       __restrict__ out,    // [B*S*EMB]
    int n_tokens)
{
    __shared__ int s_codes[TOK_PER_BLOCK * M_BYTES];   // 2 KB

    const int tid  = threadIdx.x;
    const int base = blockIdx.x * TOK_PER_BLOCK;

    // ---- Phase A: gather code rows for 64 tokens (2 independent chains/thread)
    const int t0 = tid >> 3;          // 0..31
    const int m  = tid & 7;           // 0..7
    const int t1 = t0 + 32;           // 32..63

    // 8 lanes share each id load (same cache line); two independent id loads.
    int id0 = (base + t0 < n_tokens) ? ids[base + t0] : 0;
    int id1 = (base + t1 < n_tokens) ? ids[base + t1] : 0;

    // Two independent random-row gathers (32 B rows in the 32 MB table).
    int c0 = codes[(size_t)id0 * M_BYTES + m];
    int c1 = codes[(size_t)id1 * M_BYTES + m];
    s_codes[t0 * M_BYTES + m] = c0;   // contiguous LDS write, conflict-free
    s_codes[t1 * M_BYTES + m] = c1;
    __syncthreads();

    // ---- Phase B: each wave streams 16 tokens (1 KB per token), unroll x4
    const int wave = tid >> 6;        // 0..3
    const int l    = tid & 63;
    const int lm   = l >> 3;          // code byte handled by this lane
    const int lj   = (l & 7) * 4;     // float offset within sub-embedding

    #pragma unroll
    for (int it = 0; it < 16; it += 4) {
        int   tk[4];
        float4 v[4];
        #pragma unroll
        for (int u = 0; u < 4; ++u) {
            tk[u] = (it + u) * 4 + wave;                 // 0..63, disjoint per wave
            int code = s_codes[tk[u] * M_BYTES + lm];    // LDS broadcast (8 lanes)
            v[u] = *reinterpret_cast<const float4*>(
                cent + ((size_t)(lm * 256 + code) * SUB_DIM + lj));
        }
        #pragma unroll
        for (int u = 0; u < 4; ++u) {
            int t = base + tk[u];
            if (t < n_tokens) {
                // 64 lanes -> contiguous 1 KB store
                *reinterpret_cast<float4*>(
                    out + ((size_t)t * EMB + lm * SUB_DIM + lj)) = v[u];
            }
        }
    }
}

extern "C" void kernel_launch(void* const* d_in, const int* in_sizes, int n_in,
                              void* d_out, int out_size, void* d_ws, size_t ws_size,
                              hipStream_t stream) {
    const int*   ids   = (const int*)  d_in[0];   // input_ids  [B*S] int32
    const int*   codes = (const int*)  d_in[1];   // item_codes [(N+1)*M] int32
    const float* cent  = (const float*)d_in[2];   // centroids  [M*256*SUB] float32
    float*       out   = (float*)      d_out;

    const int n_tokens = in_sizes[0];             // 102400 tokens
    const int grid = (n_tokens + TOK_PER_BLOCK - 1) / TOK_PER_BLOCK;   // 1600

    hipLaunchKernelGGL(ItemCodeLayer_30253749633338_kernel,
                       dim3(grid), dim3(BLOCK), 0, stream,
                       ids, codes, cent, out, n_tokens);
}